// Round 5
// baseline (271.227 us; speedup 1.0000x reference)
//
#include <hip/hip_runtime.h>
#include <math.h>

// (B,S,D,C) = (64, 576, 768, 200)
#define Bsz  64
#define Ssz  576
#define Dsz  768
#define Csz  200
#define NPAD 208        // 13 tiles of 16; rows >= 200 zero
#define MT   32         // rows per block (256 thr); 36864/32 = 1152 blocks
#define NKT  12         // 768 / 64

typedef short short8 __attribute__((ext_vector_type(8)));
typedef float f32x4  __attribute__((ext_vector_type(4)));

__device__ inline unsigned short f2bf_rne(float f) {
    union { float f; unsigned int u; } v; v.f = f;
    return (unsigned short)((v.u + 0x7FFFu + ((v.u >> 16) & 1u)) >> 16);
}
// two fp32 -> packed bf16x2 (round-half-up): low16 = lo, high16 = hi
__device__ inline unsigned int pack2bf(float lo, float hi) {
    union { float f; unsigned int u; } a, b; a.f = lo; b.f = hi;
    return __builtin_amdgcn_perm(b.u + 0x8000u, a.u + 0x8000u, 0x07060302u);
}

// one-time: W (200x768 fp32) -> bf16 (208x768); rows >= 200 zeroed
__global__ __launch_bounds__(256) void prep_w(const float* __restrict__ W,
                                              unsigned short* __restrict__ Wb) {
    const int i   = blockIdx.x * 256 + threadIdx.x;
    const int row = i / (Dsz / 4);
    const int col = (i % (Dsz / 4)) * 4;
    ushort4 h = {0, 0, 0, 0};
    if (row < Csz) {
        const float4 v = *(const float4*)(W + (size_t)row * Dsz + col);
        h.x = f2bf_rne(v.x); h.y = f2bf_rne(v.y); h.z = f2bf_rne(v.z); h.w = f2bf_rne(v.w);
    }
    *(ushort4*)(Wb + (size_t)row * Dsz + col) = h;
}

// global classifier runs FIRST: out[b,c] = ct[b]·gw[c] + gb[c]
__global__ __launch_bounds__(256) void gc_kernel(
    const float* __restrict__ ct, const float* __restrict__ gw,
    const float* __restrict__ gb, float* __restrict__ out) {
    const int b    = blockIdx.x;
    const int wv   = threadIdx.x >> 6;
    const int lane = threadIdx.x & 63;
    const int c    = blockIdx.y * 4 + wv;
    const float* wr = gw + (size_t)c * Dsz + lane * 12;
    const float* cr = ct + (size_t)b * Dsz + lane * 12;
    float s = 0.f;
#pragma unroll
    for (int j = 0; j < 3; ++j) {
        const float4 w = *(const float4*)(wr + 4 * j);
        const float4 x = *(const float4*)(cr + 4 * j);
        s += w.x * x.x + w.y * x.y + w.z * x.z + w.w * x.w;
    }
#pragma unroll
    for (int off = 32; off > 0; off >>= 1) s += __shfl_down(s, off, 64);
    if (lane == 0) out[b * Csz + c] = s + gb[c];
}

// 256-thread blocks, NO LDS, NO barriers. Wave w: row-group g=w>>1 (16 rows),
// tile-half h=w&1 (7 or 6 of the 13 class tiles). A from global w/ reg prefetch,
// B from global (W is L2-resident). Rowsum = exact fp32 VALU during A loads.
__global__ __launch_bounds__(256, 4) void attn_kernel(
    const float* __restrict__ X,            // (B*S, D) fp32
    const unsigned short* __restrict__ Wb,  // (NPAD, D) bf16
    const float* __restrict__ attn_b,       // (C,)
    const float* __restrict__ lam,          // (1,)
    float* __restrict__ out)                // (B, C): gscore already written
{
    const int tid  = threadIdx.x;
    const int lane = tid & 63;
    const int w    = tid >> 6;
    const int g    = w >> 1;        // 0: rows 0-15, 1: rows 16-31
    const int h    = w & 1;         // 0: tiles 0-6, 1: tiles 7-12
    const int m    = lane & 15;
    const int q    = lane >> 4;
    const int NT   = h ? 6 : 7;
    const int t0   = h * 7;
    const int rowbase = blockIdx.x * MT;
    const int bidx    = rowbase / Ssz;   // 18 blocks per batch, never crosses

    f32x4 acc[7];
#pragma unroll
    for (int t = 0; t < 7; ++t) acc[t] = (f32x4){0.f, 0.f, 0.f, 0.f};

    // A: lane owns X row (rowbase + g*16 + m), k-chunks q*8 (k2=0) and 32+q*8 (k2=1)
    const float* xp = X + (size_t)(rowbase + g * 16 + m) * Dsz + q * 8;
    // B: lane reads Wb[(t0+t)*16 + m][kt*64 + k2*32 + q*8]
    const unsigned short* wp = Wb + (size_t)m * Dsz + q * 8;

    float4 c0 = *(const float4*)(xp);
    float4 c1 = *(const float4*)(xp + 4);
    float4 c2 = *(const float4*)(xp + 32);
    float4 c3 = *(const float4*)(xp + 36);
    float rs = 0.f;   // fp32 partial rowsum of row m (this lane's k-chunks)

    for (int kt = 0; kt < NKT; ++kt) {
        // prefetch next A tile (redundant re-load on last iter; L1 hit)
        const int kn = ((kt + 1 < NKT) ? kt + 1 : kt) * 64;
        float4 n0 = *(const float4*)(xp + kn);
        float4 n1 = *(const float4*)(xp + kn + 4);
        float4 n2 = *(const float4*)(xp + kn + 32);
        float4 n3 = *(const float4*)(xp + kn + 36);

        union { short8 s; unsigned int u[4]; } a0, a1;
        a0.u[0] = pack2bf(c0.x, c0.y); a0.u[1] = pack2bf(c0.z, c0.w);
        a0.u[2] = pack2bf(c1.x, c1.y); a0.u[3] = pack2bf(c1.z, c1.w);
        a1.u[0] = pack2bf(c2.x, c2.y); a1.u[1] = pack2bf(c2.z, c2.w);
        a1.u[2] = pack2bf(c3.x, c3.y); a1.u[3] = pack2bf(c3.z, c3.w);
        rs += (c0.x + c0.y + c0.z + c0.w) + (c1.x + c1.y + c1.z + c1.w)
            + (c2.x + c2.y + c2.z + c2.w) + (c3.x + c3.y + c3.z + c3.w);

        const unsigned short* wk = wp + kt * 64;
        short8 b0[7], b1[7];
#pragma unroll
        for (int t = 0; t < 7; ++t)
            if (t < NT) b0[t] = *(const short8*)(wk + (size_t)(t0 + t) * 16 * Dsz);
#pragma unroll
        for (int t = 0; t < 7; ++t)
            if (t < NT) b1[t] = *(const short8*)(wk + (size_t)(t0 + t) * 16 * Dsz + 32);
#pragma unroll
        for (int t = 0; t < 7; ++t)
            if (t < NT) acc[t] = __builtin_amdgcn_mfma_f32_16x16x32_bf16(a0.s, b0[t], acc[t], 0, 0, 0);
#pragma unroll
        for (int t = 0; t < 7; ++t)
            if (t < NT) acc[t] = __builtin_amdgcn_mfma_f32_16x16x32_bf16(a1.s, b1[t], acc[t], 0, 0, 0);

        c0 = n0; c1 = n1; c2 = n2; c3 = n3;
    }

    // full rowsum of row m into every lane: sum partials across the 4 q-groups
    rs += __shfl_xor(rs, 16, 64);
    rs += __shfl_xor(rs, 32, 64);
    // rowsum of output-row (q*4+r) lives in lanes with m == q*4+r; pull via bpermute
    float rsv[4];
#pragma unroll
    for (int r = 0; r < 4; ++r) rsv[r] = __shfl(rs, q * 4 + r, 64);

    const float scale = lam[0] * (1.f / ((float)Ssz * (float)Dsz));

    // epilogue: C/D layout col = lane&15, row = q*4 + reg; reduce this wave's 16 rows
#pragma unroll
    for (int t = 0; t < 7; ++t) {
        if (t < NT) {
            const int c = (t0 + t) * 16 + m;
            if (c < Csz) {
                const float bias = attn_b[c];
                float s = 0.f;
#pragma unroll
                for (int r = 0; r < 4; ++r)
                    s += rsv[r] / (1.f + __expf(-(acc[t][r] + bias)));
                s += __shfl_xor(s, 16, 64);
                s += __shfl_xor(s, 32, 64);
                if (q == 0) atomicAdd(&out[bidx * Csz + c], s * scale);
            }
        }
    }
}

extern "C" void kernel_launch(void* const* d_in, const int* in_sizes, int n_in,
                              void* d_out, int out_size, void* d_ws, size_t ws_size,
                              hipStream_t stream) {
    const float* X   = (const float*)d_in[0];
    const float* ct  = (const float*)d_in[1];
    const float* aw  = (const float*)d_in[2];
    const float* ab  = (const float*)d_in[3];
    const float* gw  = (const float*)d_in[4];
    const float* gb  = (const float*)d_in[5];
    const float* lam = (const float*)d_in[6];
    float* out = (float*)d_out;
    unsigned short* Wb = (unsigned short*)d_ws;   // 208*768*2 = 320 KB

    prep_w<<<(NPAD * Dsz / 4) / 256, 256, 0, stream>>>(aw, Wb);
    gc_kernel<<<dim3(Bsz, Csz / 4), 256, 0, stream>>>(ct, gw, gb, out);
    attn_kernel<<<(Bsz * Ssz) / MT, 256, 0, stream>>>(X, Wb, ab, lam, out);
}

// Round 6
// 210.755 us; speedup vs baseline: 1.2869x; 1.2869x over previous
//
#include <hip/hip_runtime.h>
#include <math.h>

// (B,S,D,C) = (64, 576, 768, 200)
#define Bsz  64
#define Ssz  576
#define Dsz  768
#define Csz  200
#define NPAD 208        // 13 tiles of 16: 0..199 classes, col 200 = ones (rowsum), rest zero
#define MT   32         // rows per block; grid 1152
#define BK   64
#define NKT  12

typedef short short8 __attribute__((ext_vector_type(8)));
typedef float f32x4  __attribute__((ext_vector_type(4)));

#define AS_GLOBAL __attribute__((address_space(1)))
#define AS_LDS    __attribute__((address_space(3)))

__device__ inline unsigned short f2bf_rne(float f) {
    union { float f; unsigned int u; } v; v.f = f;
    return (unsigned short)((v.u + 0x7FFFu + ((v.u >> 16) & 1u)) >> 16);
}
// two fp32 -> packed bf16x2 (round-half-up): low16 = lo, high16 = hi
__device__ inline unsigned int pack2bf(float lo, float hi) {
    union { float f; unsigned int u; } a, b; a.f = lo; b.f = hi;
    return __builtin_amdgcn_perm(b.u + 0x8000u, a.u + 0x8000u, 0x07060302u);
}
// async 16B-per-lane global -> LDS (dest = wave-uniform base + lane*16)
__device__ inline void gload16(const unsigned short* g, unsigned short* l) {
    __builtin_amdgcn_global_load_lds((const AS_GLOBAL unsigned int*)g,
                                     (AS_LDS unsigned int*)l, 16, 0, 0);
}
__device__ inline void gload16f(const float* g, float* l) {
    __builtin_amdgcn_global_load_lds((const AS_GLOBAL unsigned int*)g,
                                     (AS_LDS unsigned int*)l, 16, 0, 0);
}

// one-time: W (200x768 fp32) -> bf16 (208x768); row 200 = 1.0 (rowsum), 201..207 = 0
__global__ __launch_bounds__(256) void prep_w(const float* __restrict__ W,
                                              unsigned short* __restrict__ Wb) {
    const int i   = blockIdx.x * 256 + threadIdx.x;
    const int row = i / (Dsz / 4);
    const int col = (i % (Dsz / 4)) * 4;
    ushort4 h;
    if (row < Csz) {
        const float4 v = *(const float4*)(W + (size_t)row * Dsz + col);
        h.x = f2bf_rne(v.x); h.y = f2bf_rne(v.y); h.z = f2bf_rne(v.z); h.w = f2bf_rne(v.w);
    } else if (row == Csz) {
        h.x = h.y = h.z = h.w = 0x3F80;   // bf16 1.0
    } else {
        h.x = h.y = h.z = h.w = 0;
    }
    *(ushort4*)(Wb + (size_t)row * Dsz + col) = h;
}

// global classifier runs FIRST: out[b,c] = ct[b]·gw[c] + gb[c]
__global__ __launch_bounds__(256) void gc_kernel(
    const float* __restrict__ ct, const float* __restrict__ gw,
    const float* __restrict__ gb, float* __restrict__ out) {
    const int b    = blockIdx.x;
    const int wv   = threadIdx.x >> 6;
    const int lane = threadIdx.x & 63;
    const int c    = blockIdx.y * 4 + wv;
    const float* wr = gw + (size_t)c * Dsz + lane * 12;
    const float* cr = ct + (size_t)b * Dsz + lane * 12;
    float s = 0.f;
#pragma unroll
    for (int j = 0; j < 3; ++j) {
        const float4 w = *(const float4*)(wr + 4 * j);
        const float4 x = *(const float4*)(cr + 4 * j);
        s += w.x * x.x + w.y * x.y + w.z * x.z + w.w * x.w;
    }
#pragma unroll
    for (int off = 32; off > 0; off >>= 1) s += __shfl_down(s, off, 64);
    if (lane == 0) out[b * Csz + c] = s + gb[c];
}

// ALL global traffic via global_load_lds DMA, double-buffered, 1 barrier/iter.
// Wave (g,h): g = row-half (16 rows), h = class-half (tiles 0-6 / 7-12).
__global__ __launch_bounds__(256, 4) void attn_kernel(
    const float* __restrict__ X,            // (B*S, D) fp32
    const unsigned short* __restrict__ Wb,  // (NPAD, D) bf16
    const float* __restrict__ attn_b,       // (C,)
    const float* __restrict__ lam,          // (1,)
    float* __restrict__ out)                // (B, C): gscore already written
{
    __shared__ float sX[2][MT * BK];               // 2 x 8 KB, 16B chunks XOR-swizzled
    __shared__ unsigned short sW[2][NPAD * BK];    // 2 x 26.6 KB, XOR-swizzled
    __shared__ float rowsumL[MT];

    const int tid  = threadIdx.x;
    const int lane = tid & 63;
    const int w    = tid >> 6;
    const int g    = w >> 1;
    const int h    = w & 1;
    const int m    = lane & 15;
    const int q    = lane >> 4;
    const int NT   = h ? 6 : 7;
    const int t0   = h * 7;
    const int rowbase = blockIdx.x * MT;
    const int bidx    = rowbase / Ssz;   // 18 blocks/batch, never crosses

    // ---- X DMA map: 512 chunks/buffer; wave w issues slots s=(w*2+j)*64+lane, j=0,1
    // row r = s>>4, lds-chunk = s&15, global chunk c = (s&15) ^ (r&15)
    const int sx0 = (w * 2) * 64 + lane;
    const int sx1 = sx0 + 64;
    const int xr0 = sx0 >> 4, xc0 = (sx0 & 15) ^ (xr0 & 15);
    const int xr1 = sx1 >> 4, xc1 = (sx1 & 15) ^ (xr1 & 15);
    const float* xg0 = X + (size_t)(rowbase + xr0) * Dsz + xc0 * 4;
    const float* xg1 = X + (size_t)(rowbase + xr1) * Dsz + xc1 * 4;

    // ---- W DMA map (R3-verified): 1664 chunks = 26 groups, waves take 7/7/6/6
    const int wn   = (w < 2) ? 7 : 6;
    const int grp0 = (w < 2) ? w * 7 : 14 + (w - 2) * 6;
    const int s0    = grp0 * 64 + lane;
    const int wrow0 = s0 >> 3;
    const int wcg   = (s0 & 7) ^ (wrow0 & 7);     // invariant under row += 8
    const unsigned short* wg0 = Wb + (size_t)wrow0 * Dsz + wcg * 8;

    f32x4 acc[7];
#pragma unroll
    for (int t = 0; t < 7; ++t) acc[t] = (f32x4){0.f, 0.f, 0.f, 0.f};

    // ---- prologue: tile 0 into buffer 0
    gload16f(xg0, &sX[0][(w * 2 + 0) * 256]);
    gload16f(xg1, &sX[0][(w * 2 + 1) * 256]);
#pragma unroll
    for (int j = 0; j < 7; ++j)
        if (j < wn) gload16(wg0 + (size_t)8 * j * Dsz, &sW[0][(grp0 + j) * 512]);

    const int rA  = g * 16 + m;      // this lane's X row (local)
    const int rAx = rA & 15;         // swizzle key

    for (int kt = 0; kt < NKT; ++kt) {
        const int p = kt & 1;
        // drain: buffer p's DMA (issued last iter) complete; buffer p^1 free
        __syncthreads();
        if (kt + 1 < NKT) {
            const int kk = (kt + 1) * BK;
            gload16f(xg0 + kk, &sX[p ^ 1][(w * 2 + 0) * 256]);
            gload16f(xg1 + kk, &sX[p ^ 1][(w * 2 + 1) * 256]);
#pragma unroll
            for (int j = 0; j < 7; ++j)
                if (j < wn) gload16(wg0 + (size_t)(kk + 8 * j * Dsz), &sW[p ^ 1][(grp0 + j) * 512]);
        }
        // ---- A frags from LDS fp32 (+ convert), B frags from LDS bf16
#pragma unroll
        for (int k2 = 0; k2 < 2; ++k2) {
            const int cA = k2 * 8 + 2 * q;
            const float4 alo = *(const float4*)&sX[p][(rA * 16 + (cA ^ rAx)) * 4];
            const float4 ahi = *(const float4*)&sX[p][(rA * 16 + ((cA + 1) ^ rAx)) * 4];
            union { short8 s; unsigned int u[4]; } A;
            A.u[0] = pack2bf(alo.x, alo.y); A.u[1] = pack2bf(alo.z, alo.w);
            A.u[2] = pack2bf(ahi.x, ahi.y); A.u[3] = pack2bf(ahi.z, ahi.w);
            const unsigned short* wb = &sW[p][m * 64 + ((k2 * 4 + q) ^ (m & 7)) * 8];
#pragma unroll
            for (int t = 0; t < 7; ++t) {
                if (t < NT) {
                    const short8 bf = *(const short8*)(wb + (t0 + t) * 1024);
                    acc[t] = __builtin_amdgcn_mfma_f32_16x16x32_bf16(A.s, bf, acc[t], 0, 0, 0);
                }
            }
        }
    }

    // ---- rowsum via ones-column: tile 12 (h=1 local acc[5]), col 200 => lanes m==8
    if (h == 1 && m == 8) {
#pragma unroll
        for (int r = 0; r < 4; ++r) rowsumL[g * 16 + q * 4 + r] = acc[5][r];
    }
    __syncthreads();
    float rsv[4];
#pragma unroll
    for (int r = 0; r < 4; ++r) rsv[r] = rowsumL[g * 16 + q * 4 + r];

    const float scale = lam[0] * (1.f / ((float)Ssz * (float)Dsz));

    // ---- epilogue: C/D col = lane&15, row = q*4+reg; reduce wave's 16 rows
#pragma unroll
    for (int t = 0; t < 7; ++t) {
        if (t < NT) {
            const int c = (t0 + t) * 16 + m;
            if (c < Csz) {
                const float bias = attn_b[c];
                float s = 0.f;
#pragma unroll
                for (int r = 0; r < 4; ++r)
                    s += rsv[r] / (1.f + __expf(-(acc[t][r] + bias)));
                s += __shfl_xor(s, 16, 64);
                s += __shfl_xor(s, 32, 64);
                if (q == 0) atomicAdd(&out[bidx * Csz + c], s * scale);
            }
        }
    }
}

extern "C" void kernel_launch(void* const* d_in, const int* in_sizes, int n_in,
                              void* d_out, int out_size, void* d_ws, size_t ws_size,
                              hipStream_t stream) {
    const float* X   = (const float*)d_in[0];
    const float* ct  = (const float*)d_in[1];
    const float* aw  = (const float*)d_in[2];
    const float* ab  = (const float*)d_in[3];
    const float* gw  = (const float*)d_in[4];
    const float* gb  = (const float*)d_in[5];
    const float* lam = (const float*)d_in[6];
    float* out = (float*)d_out;
    unsigned short* Wb = (unsigned short*)d_ws;   // 208*768*2 = 320 KB

    prep_w<<<(NPAD * Dsz / 4) / 256, 256, 0, stream>>>(aw, Wb);
    gc_kernel<<<dim3(Bsz, Csz / 4), 256, 0, stream>>>(ct, gw, gb, out);
    attn_kernel<<<(Bsz * Ssz) / MT, 256, 0, stream>>>(X, Wb, ab, lam, out);
}